// Round 2
// baseline (969.101 us; speedup 1.0000x reference)
//
#include <hip/hip_runtime.h>
#include <cstdint>
#include <cstdio>

typedef __bf16 bf16x8 __attribute__((ext_vector_type(8)));
typedef float  f32x4  __attribute__((ext_vector_type(4)));
typedef const __attribute__((address_space(1))) void* gas_ptr;
typedef __attribute__((address_space(3))) void* las_ptr;

__device__ __forceinline__ uint16_t f32_to_bf16_rne(float f){
  uint32_t u = __builtin_bit_cast(uint32_t, f);
  u += 0x7FFFu + ((u >> 16) & 1u);
  return (uint16_t)(u >> 16);
}

__device__ __forceinline__ float gelu_exact(float x){
  return 0.5f * x * (1.f + erff(x * 0.7071067811865475f));
}

// ---------------------------------------------------------------------------
// GEMM: C[M,N] = A[M,K](bf16) * Bt[N,K](bf16)^T + bias, epilogue variants.
// EPI 0: Cf = acc + bias
// EPI 1: Cf = gelu(acc + bias)
// EPI 2: Cf = acc + bias + aux[m][n]
// EPI 3: Cb = bf16((acc + bias) * aux[m][n])
// 128x128 tile, BK=32, 4 waves, global_load_lds(16B), XOR swizzle on k-chunks.
// ---------------------------------------------------------------------------
template<int EPI>
__global__ __launch_bounds__(256)
void gemm_kernel(const uint16_t* __restrict__ A, const uint16_t* __restrict__ Bt,
                 const float* __restrict__ bias, const float* __restrict__ aux,
                 float* __restrict__ Cf, uint16_t* __restrict__ Cb,
                 int M, int N, int K)
{
  __shared__ alignas(16) uint16_t lA[128*32];
  __shared__ alignas(16) uint16_t lB[128*32];
  const int tid  = threadIdx.x;
  const int wid  = tid >> 6;
  const int lane = tid & 63;
  const int n0 = blockIdx.x * 128;
  const int m0 = blockIdx.y * 128;
  const int wr = wid >> 1, wc = wid & 1;

  // staging: slot s holds 16B at lds byte s*16 = row*64 + cp*16 (tile [128][32] bf16)
  // slot (row,cp) gets global k-chunk c = cp ^ ((row>>1)&3)  (2-way-free swizzle)
  const int s0 = tid, s1 = 256 + tid;
  const int r0 = s0 >> 2, c0 = (s0 & 3) ^ ((r0 >> 1) & 3);
  const int r1 = s1 >> 2, c1 = (s1 & 3) ^ ((r1 >> 1) & 3);
  const uint16_t* gA0 = A  + (size_t)(m0 + r0) * K + c0 * 8;
  const uint16_t* gA1 = A  + (size_t)(m0 + r1) * K + c1 * 8;
  const uint16_t* gB0 = Bt + (size_t)(n0 + r0) * K + c0 * 8;
  const uint16_t* gB1 = Bt + (size_t)(n0 + r1) * K + c1 * 8;
  uint16_t* lA0 = &lA[(wid * 64) * 8];
  uint16_t* lA1 = &lA[(256 + wid * 64) * 8];
  uint16_t* lB0 = &lB[(wid * 64) * 8];
  uint16_t* lB1 = &lB[(256 + wid * 64) * 8];

  f32x4 acc[4][4];
  const f32x4 fzero = {0.f, 0.f, 0.f, 0.f};
#pragma unroll
  for (int m = 0; m < 4; m++)
#pragma unroll
    for (int n = 0; n < 4; n++) acc[m][n] = fzero;

  const int la = lane & 15, lb = lane >> 4;
  int offA[4], offB[4];
#pragma unroll
  for (int m = 0; m < 4; m++){
    int row = wr*64 + m*16 + la;
    offA[m] = row*64 + ((lb ^ ((row >> 1) & 3)) << 4);
  }
#pragma unroll
  for (int n = 0; n < 4; n++){
    int row = wc*64 + n*16 + la;
    offB[n] = row*64 + ((lb ^ ((row >> 1) & 3)) << 4);
  }
  const char* lAc = (const char*)lA;
  const char* lBc = (const char*)lB;

  for (int ks = 0; ks < K; ks += 32){
    __syncthreads();
    __builtin_amdgcn_global_load_lds((gas_ptr)(gA0 + ks), (las_ptr)lA0, 16, 0, 0);
    __builtin_amdgcn_global_load_lds((gas_ptr)(gA1 + ks), (las_ptr)lA1, 16, 0, 0);
    __builtin_amdgcn_global_load_lds((gas_ptr)(gB0 + ks), (las_ptr)lB0, 16, 0, 0);
    __builtin_amdgcn_global_load_lds((gas_ptr)(gB1 + ks), (las_ptr)lB1, 16, 0, 0);
    __syncthreads();
    bf16x8 af[4], bfr[4];
#pragma unroll
    for (int m = 0; m < 4; m++) af[m]  = *(const bf16x8*)(lAc + offA[m]);
#pragma unroll
    for (int n = 0; n < 4; n++) bfr[n] = *(const bf16x8*)(lBc + offB[n]);
#pragma unroll
    for (int m = 0; m < 4; m++)
#pragma unroll
      for (int n = 0; n < 4; n++)
        acc[m][n] = __builtin_amdgcn_mfma_f32_16x16x32_bf16(af[m], bfr[n], acc[m][n], 0, 0, 0);
  }

  // epilogue: row = m0+wr*64+m*16+(lane>>4)*4+r, col = n0+wc*64+n*16+(lane&15)
#pragma unroll
  for (int n = 0; n < 4; n++){
    int col = n0 + wc*64 + n*16 + la;
    float bv = bias[col];
#pragma unroll
    for (int m = 0; m < 4; m++){
      int rbase = m0 + wr*64 + m*16 + lb*4;
#pragma unroll
      for (int r = 0; r < 4; r++){
        int row = rbase + r;
        size_t idx = (size_t)row * N + col;
        float v = acc[m][n][r] + bv;
        if constexpr (EPI == 1) v = gelu_exact(v);
        if constexpr (EPI == 2) v += aux[idx];
        if constexpr (EPI == 3) Cb[idx] = f32_to_bf16_rne(v * aux[idx]);
        else                    Cf[idx] = v;
      }
    }
  }
}

// ---------------------------------------------------------------------------
// Convert + transpose: in[R][C] f32 -> out[C][R] bf16. 64x64 tiles.
// ---------------------------------------------------------------------------
__global__ __launch_bounds__(256)
void cvt_transpose(const float* __restrict__ in, uint16_t* __restrict__ out, int R, int C)
{
  __shared__ float tile[64][65];
  const int r0 = blockIdx.y * 64, c0 = blockIdx.x * 64;
  const int t = threadIdx.x;
  const int lc = (t & 15) * 4;
  const int lr0 = t >> 4;
#pragma unroll
  for (int j = 0; j < 4; j++){
    int lr = lr0 + j*16;
    float4 v = *(const float4*)(in + (size_t)(r0 + lr) * C + c0 + lc);
    tile[lr][lc+0] = v.x; tile[lr][lc+1] = v.y; tile[lr][lc+2] = v.z; tile[lr][lc+3] = v.w;
  }
  __syncthreads();
  const int oc = t >> 2;
  const int rseg = (t & 3) * 16;
  alignas(16) uint16_t tmp[16];
#pragma unroll
  for (int j = 0; j < 16; j++) tmp[j] = f32_to_bf16_rne(tile[rseg + j][oc]);
  uint4* dst = (uint4*)(out + (size_t)(c0 + oc) * R + r0 + rseg);
  dst[0] = *(const uint4*)(&tmp[0]);
  dst[1] = *(const uint4*)(&tmp[8]);
}

// ---------------------------------------------------------------------------
// RMSNorm: per row of D f32 -> bf16. grid = rows, block = 256 (8 elems/thread).
// ---------------------------------------------------------------------------
__global__ __launch_bounds__(256)
void rmsnorm_kernel(const float* __restrict__ x, const float* __restrict__ w,
                    uint16_t* __restrict__ out, int D)
{
  const int row = blockIdx.x;
  const float* xr = x + (size_t)row * D;
  const int base = threadIdx.x * 8;
  float4 va = *(const float4*)(xr + base);
  float4 vb = *(const float4*)(xr + base + 4);
  float ss = va.x*va.x + va.y*va.y + va.z*va.z + va.w*va.w
           + vb.x*vb.x + vb.y*vb.y + vb.z*vb.z + vb.w*vb.w;
#pragma unroll
  for (int o = 32; o > 0; o >>= 1) ss += __shfl_xor(ss, o);
  __shared__ float red[4];
  if ((threadIdx.x & 63) == 0) red[threadIdx.x >> 6] = ss;
  __syncthreads();
  float tot = red[0] + red[1] + red[2] + red[3];
  float inv = rsqrtf(tot / (float)D + 1e-8f);
  float4 wa = *(const float4*)(w + base);
  float4 wb = *(const float4*)(w + base + 4);
  alignas(16) uint16_t tmp[8];
  tmp[0] = f32_to_bf16_rne(va.x * wa.x * inv);
  tmp[1] = f32_to_bf16_rne(va.y * wa.y * inv);
  tmp[2] = f32_to_bf16_rne(va.z * wa.z * inv);
  tmp[3] = f32_to_bf16_rne(va.w * wa.w * inv);
  tmp[4] = f32_to_bf16_rne(vb.x * wb.x * inv);
  tmp[5] = f32_to_bf16_rne(vb.y * wb.y * inv);
  tmp[6] = f32_to_bf16_rne(vb.z * wb.z * inv);
  tmp[7] = f32_to_bf16_rne(vb.w * wb.w * inv);
  *(uint4*)(out + (size_t)row * D + base) = *(const uint4*)tmp;
}

// ---------------------------------------------------------------------------
// Depthwise causal conv K=4 along t. Writes f32 and bf16 copies.
// grid (H/256, S/128, B)
// ---------------------------------------------------------------------------
__global__ __launch_bounds__(256)
void conv_kernel(const float* __restrict__ xin, const float* __restrict__ cw,
                 const float* __restrict__ cb, float* __restrict__ yf,
                 uint16_t* __restrict__ yb, int S, int H)
{
  const int h = blockIdx.x * 256 + threadIdx.x;
  const int b = blockIdx.z;
  const int t0 = blockIdx.y * 128;
  const float w0 = cw[h], w1 = cw[H + h], w2 = cw[2*H + h], w3 = cw[3*H + h];
  const float bias = cb[h];
  const size_t colbase = (size_t)b * S * H + h;
  float xm3 = (t0 >= 3) ? xin[colbase + (size_t)(t0-3)*H] : 0.f;
  float xm2 = (t0 >= 2) ? xin[colbase + (size_t)(t0-2)*H] : 0.f;
  float xm1 = (t0 >= 1) ? xin[colbase + (size_t)(t0-1)*H] : 0.f;
  for (int t = t0; t < t0 + 128; ++t){
    size_t idx = colbase + (size_t)t * H;
    float xt = xin[idx];
    float y = w0*xm3 + w1*xm2 + w2*xm1 + w3*xt + bias;
    yf[idx] = y;
    yb[idx] = f32_to_bf16_rne(y);
    xm3 = xm2; xm2 = xm1; xm1 = xt;
  }
}

// ---------------------------------------------------------------------------
// RG-LRU chunked scan. a = exp(-8*softplus(ap)*sigmoid(rpre)),
// b = sqrt(-expm1(2*log_a)) * sigmoid(ipre) * conv.
// ---------------------------------------------------------------------------
__device__ __forceinline__ void rglru_ab(float rp, float ip, float xc, float coef,
                                         float& a, float& bb)
{
  float r  = 1.f / (1.f + expf(-rp));
  float la = coef * r;
  a = expf(la);
  float mult = sqrtf(-expm1f(2.f * la));
  float ig = 1.f / (1.f + expf(-ip));
  bb = mult * ig * xc;
}

__global__ __launch_bounds__(256)
void scan_phase1(const float* __restrict__ rpre, const float* __restrict__ ipre,
                 const float* __restrict__ conv, const float* __restrict__ ap,
                 float* __restrict__ SA, float* __restrict__ SB,
                 int S, int H, int T0, int NC)
{
  const int h = blockIdx.x * 256 + threadIdx.x;
  const int j = blockIdx.y, b = blockIdx.z;
  const float coef = -8.f * log1pf(expf(ap[h]));
  size_t base = ((size_t)b * S + (size_t)j * T0) * H + h;
  float A = 1.f, Bc = 0.f;
  for (int t = 0; t < T0; ++t){
    size_t idx = base + (size_t)t * H;
    float a, bb; rglru_ab(rpre[idx], ipre[idx], conv[idx], coef, a, bb);
    A *= a; Bc = a * Bc + bb;
  }
  size_t o = ((size_t)b * NC + j) * H + h;
  SA[o] = A; SB[o] = Bc;
}

__global__ __launch_bounds__(256)
void scan_phase2(const float* __restrict__ SA, const float* __restrict__ SB,
                 float* __restrict__ SH, int H, int NC)
{
  const int h = blockIdx.x * 256 + threadIdx.x;
  const int b = blockIdx.y;
  float hh = 0.f;
  for (int j = 0; j < NC; ++j){
    size_t o = ((size_t)b * NC + j) * H + h;
    SH[o] = hh;
    hh = SA[o] * hh + SB[o];
  }
}

__global__ __launch_bounds__(256)
void scan_phase3(const float* __restrict__ rpre, const float* __restrict__ ipre,
                 const float* __restrict__ conv, const float* __restrict__ ap,
                 const float* __restrict__ SH, const float* __restrict__ left,
                 uint16_t* __restrict__ lr, int S, int H, int T0, int NC)
{
  const int h = blockIdx.x * 256 + threadIdx.x;
  const int j = blockIdx.y, b = blockIdx.z;
  const float coef = -8.f * log1pf(expf(ap[h]));
  float hh = SH[((size_t)b * NC + j) * H + h];
  size_t base = ((size_t)b * S + (size_t)j * T0) * H + h;
  for (int t = 0; t < T0; ++t){
    size_t idx = base + (size_t)t * H;
    float a, bb; rglru_ab(rpre[idx], ipre[idx], conv[idx], coef, a, bb);
    hh = a * hh + bb;
    lr[idx] = f32_to_bf16_rne(left[idx] * hh);
  }
}

// ---------------------------------------------------------------------------
extern "C" void kernel_launch(void* const* d_in, const int* in_sizes, int n_in,
                              void* d_out, int out_size, void* d_ws, size_t ws_size,
                              hipStream_t stream)
{
  const int B = 2, S = 2048, D = 2048, H = 2048, F = 6144;
  const int M = B * S;            // 4096
  const int NC = 32, T0 = S / NC; // scan chunking

  const float* x       = (const float*)d_in[0];
  const float* norm1_w = (const float*)d_in[1];
  const float* left_W  = (const float*)d_in[2];
  const float* left_b  = (const float*)d_in[3];
  const float* right_W = (const float*)d_in[4];
  const float* right_b = (const float*)d_in[5];
  const float* conv_w  = (const float*)d_in[6];
  const float* conv_b  = (const float*)d_in[7];
  const float* ga_W    = (const float*)d_in[8];
  const float* ga_b    = (const float*)d_in[9];
  const float* gx_W    = (const float*)d_in[10];
  const float* gx_b    = (const float*)d_in[11];
  const float* a_param = (const float*)d_in[12];
  const float* out_W   = (const float*)d_in[13];
  const float* out_b   = (const float*)d_in[14];
  const float* norm2_w = (const float*)d_in[15];
  const float* up1_W   = (const float*)d_in[16];
  const float* up1_b   = (const float*)d_in[17];
  const float* up2_W   = (const float*)d_in[18];
  const float* up2_b   = (const float*)d_in[19];
  const float* down_W  = (const float*)d_in[20];
  const float* down_b  = (const float*)d_in[21];

  char* ws = (char*)d_ws;
  size_t off = 0;
  auto alloc = [&](size_t bytes) -> char* {
    char* p = ws + off; off += (bytes + 255) & ~(size_t)255; return p;
  };
  // Overlays: T1 [M][F] f32 (96MB) overlays LEFT+RPRE+CONV (3x32MB).
  //           G  [M][F] bf16 (48MB) overlays IPRE+LR (32+16MB).
  uint16_t* WT   = (uint16_t*)alloc((size_t)F * D * 2);  // weight bf16^T scratch (max 6144x2048)
  uint16_t* XN   = (uint16_t*)alloc((size_t)M * D * 2);  // xn bf16; reused as conv bf16
  float*    LEFT = (float*)   alloc((size_t)M * H * 4);
  float*    RPRE = (float*)   alloc((size_t)M * H * 4);
  float*    CONV = (float*)   alloc((size_t)M * H * 4);
  float*    IPRE = (float*)   alloc((size_t)M * H * 4);
  uint16_t* LR   = (uint16_t*)alloc((size_t)M * H * 2);
  float*    X1   = (float*)   alloc((size_t)M * D * 4);
  uint16_t* X1N  = (uint16_t*)alloc((size_t)M * D * 2);
  float*    SA   = (float*)   alloc((size_t)B * NC * H * 4);
  float*    SB   = (float*)   alloc((size_t)B * NC * H * 4);
  float*    SH   = (float*)   alloc((size_t)B * NC * H * 4);
  float*    T1   = LEFT;            // [M][F] f32
  uint16_t* G    = (uint16_t*)IPRE; // [M][F] bf16

  if (off > ws_size) {
    fprintf(stderr, "kernel_launch: ws too small, need %zu have %zu\n", off, ws_size);
    return;
  }

  float* OUT = (float*)d_out;
  dim3 blk(256);

  // 1. xn = rmsnorm(x)
  rmsnorm_kernel<<<M, blk, 0, stream>>>(x, norm1_w, XN, D);

  // 2. left = gelu(xn @ left_W + left_b)
  cvt_transpose<<<dim3(H/64, D/64), blk, 0, stream>>>(left_W, WT, D, H);
  gemm_kernel<1><<<dim3(H/128, M/128), blk, 0, stream>>>(XN, WT, left_b, nullptr, LEFT, nullptr, M, H, D);

  // 3. rightpre = xn @ right_W + right_b
  cvt_transpose<<<dim3(H/64, D/64), blk, 0, stream>>>(right_W, WT, D, H);
  gemm_kernel<0><<<dim3(H/128, M/128), blk, 0, stream>>>(XN, WT, right_b, nullptr, RPRE, nullptr, M, H, D);

  // 4. conv (causal depthwise) -> CONV f32 + XN bf16 (XN dead as xn now)
  conv_kernel<<<dim3(H/256, S/128, B), blk, 0, stream>>>(RPRE, conv_w, conv_b, CONV, XN, S, H);

  // 5. gate preacts
  cvt_transpose<<<dim3(H/64, H/64), blk, 0, stream>>>(ga_W, WT, H, H);
  gemm_kernel<0><<<dim3(H/128, M/128), blk, 0, stream>>>(XN, WT, ga_b, nullptr, RPRE, nullptr, M, H, H);
  cvt_transpose<<<dim3(H/64, H/64), blk, 0, stream>>>(gx_W, WT, H, H);
  gemm_kernel<0><<<dim3(H/128, M/128), blk, 0, stream>>>(XN, WT, gx_b, nullptr, IPRE, nullptr, M, H, H);

  // 6. rg-lru chunked scan; phase3 fuses lr = bf16(left * h)
  scan_phase1<<<dim3(H/256, NC, B), blk, 0, stream>>>(RPRE, IPRE, CONV, a_param, SA, SB, S, H, T0, NC);
  scan_phase2<<<dim3(H/256, B), blk, 0, stream>>>(SA, SB, SH, H, NC);
  scan_phase3<<<dim3(H/256, NC, B), blk, 0, stream>>>(RPRE, IPRE, CONV, a_param, SH, LEFT, LR, S, H, T0, NC);

  // 7. x1 = lr @ out_W + out_b + x
  cvt_transpose<<<dim3(D/64, H/64), blk, 0, stream>>>(out_W, WT, H, D);
  gemm_kernel<2><<<dim3(D/128, M/128), blk, 0, stream>>>(LR, WT, out_b, x, X1, nullptr, M, D, H);

  // 8. x1n = rmsnorm(x1)
  rmsnorm_kernel<<<M, blk, 0, stream>>>(X1, norm2_w, X1N, D);

  // 9. t1 = gelu(x1n @ up1_W + up1_b)
  cvt_transpose<<<dim3(F/64, D/64), blk, 0, stream>>>(up1_W, WT, D, F);
  gemm_kernel<1><<<dim3(F/128, M/128), blk, 0, stream>>>(X1N, WT, up1_b, nullptr, T1, nullptr, M, F, D);

  // 10. g = bf16(t1 * (x1n @ up2_W + up2_b))
  cvt_transpose<<<dim3(F/64, D/64), blk, 0, stream>>>(up2_W, WT, D, F);
  gemm_kernel<3><<<dim3(F/128, M/128), blk, 0, stream>>>(X1N, WT, up2_b, T1, nullptr, G, M, F, D);

  // 11. out = g @ down_W + down_b + x1
  cvt_transpose<<<dim3(D/64, F/64), blk, 0, stream>>>(down_W, WT, F, D);
  gemm_kernel<2><<<dim3(D/128, M/128), blk, 0, stream>>>(G, WT, down_b, X1, OUT, nullptr, M, D, F);
}

// Round 4
// 951.819 us; speedup vs baseline: 1.0182x; 1.0182x over previous
//
#include <hip/hip_runtime.h>
#include <cstdint>
#include <cstdio>

typedef __bf16 bf16x8 __attribute__((ext_vector_type(8)));
typedef float  f32x4  __attribute__((ext_vector_type(4)));
typedef const __attribute__((address_space(1))) void* gas_ptr;
typedef __attribute__((address_space(3))) void* las_ptr;

__device__ __forceinline__ uint16_t f32_to_bf16_rne(float f){
  uint32_t u = __builtin_bit_cast(uint32_t, f);
  u += 0x7FFFu + ((u >> 16) & 1u);
  return (uint16_t)(u >> 16);
}
__device__ __forceinline__ float bf16_to_f32(uint16_t h){
  uint32_t u = (uint32_t)h << 16;
  return __builtin_bit_cast(float, u);
}
__device__ __forceinline__ float gelu_exact(float x){
  return 0.5f * x * (1.f + erff(x * 0.7071067811865475f));
}

// ---------------------------------------------------------------------------
// GEMM: C[M,N] = A[M,K](bf16) * Bt[N,K](bf16)^T + bias, epilogue variants.
// EPI 0: Cf[idx] = v + auxF[idx]                       (f32 out, f32 residual)
// EPI 1: col<SPLIT: Cb0 = bf16(gelu(v)) ; else Cb1 = bf16(v)   (split halves)
// EPI 2: Cb0[row*N+col] = bf16(v)                      (raw bf16, merged buf)
// EPI 3: Cb0[row*N+col] = bf16(v * bf16(auxB[idx]))    (gated mul)
// bias: col<SPLIT -> bias0[col], else bias1[col-SPLIT].
// 128x128 tile, BK=32, 4 waves, global_load_lds(16B), XOR swizzle on k-chunks.
// ---------------------------------------------------------------------------
template<int EPI>
__global__ __launch_bounds__(256)
void gemm_kernel(const uint16_t* __restrict__ A, const uint16_t* __restrict__ Bt,
                 const float* __restrict__ bias0, const float* __restrict__ bias1,
                 const float* __restrict__ auxF, const uint16_t* __restrict__ auxB,
                 float* __restrict__ Cf, uint16_t* __restrict__ Cb0, uint16_t* __restrict__ Cb1,
                 int M, int N, int K, int SPLIT)
{
  __shared__ alignas(16) uint16_t lA[128*32];
  __shared__ alignas(16) uint16_t lB[128*32];
  const int tid  = threadIdx.x;
  const int wid  = tid >> 6;
  const int lane = tid & 63;
  const int n0 = blockIdx.x * 128;
  const int m0 = blockIdx.y * 128;
  const int wr = wid >> 1, wc = wid & 1;

  // staging: slot s holds 16B at lds byte s*16 = row*64 + cp*16 (tile [128][32] bf16)
  // slot (row,cp) gets global k-chunk c = cp ^ ((row>>1)&3)  (2-way-free swizzle)
  const int s0 = tid, s1 = 256 + tid;
  const int r0 = s0 >> 2, c0 = (s0 & 3) ^ ((r0 >> 1) & 3);
  const int r1 = s1 >> 2, c1 = (s1 & 3) ^ ((r1 >> 1) & 3);
  const uint16_t* gA0 = A  + (size_t)(m0 + r0) * K + c0 * 8;
  const uint16_t* gA1 = A  + (size_t)(m0 + r1) * K + c1 * 8;
  const uint16_t* gB0 = Bt + (size_t)(n0 + r0) * K + c0 * 8;
  const uint16_t* gB1 = Bt + (size_t)(n0 + r1) * K + c1 * 8;
  uint16_t* lA0 = &lA[(wid * 64) * 8];
  uint16_t* lA1 = &lA[(256 + wid * 64) * 8];
  uint16_t* lB0 = &lB[(wid * 64) * 8];
  uint16_t* lB1 = &lB[(256 + wid * 64) * 8];

  f32x4 acc[4][4];
  const f32x4 fzero = {0.f, 0.f, 0.f, 0.f};
#pragma unroll
  for (int m = 0; m < 4; m++)
#pragma unroll
    for (int n = 0; n < 4; n++) acc[m][n] = fzero;

  const int la = lane & 15, lb = lane >> 4;
  int offA[4], offB[4];
#pragma unroll
  for (int m = 0; m < 4; m++){
    int row = wr*64 + m*16 + la;
    offA[m] = row*64 + ((lb ^ ((row >> 1) & 3)) << 4);
  }
#pragma unroll
  for (int n = 0; n < 4; n++){
    int row = wc*64 + n*16 + la;
    offB[n] = row*64 + ((lb ^ ((row >> 1) & 3)) << 4);
  }
  const char* lAc = (const char*)lA;
  const char* lBc = (const char*)lB;

  for (int ks = 0; ks < K; ks += 32){
    __syncthreads();
    __builtin_amdgcn_global_load_lds((gas_ptr)(gA0 + ks), (las_ptr)lA0, 16, 0, 0);
    __builtin_amdgcn_global_load_lds((gas_ptr)(gA1 + ks), (las_ptr)lA1, 16, 0, 0);
    __builtin_amdgcn_global_load_lds((gas_ptr)(gB0 + ks), (las_ptr)lB0, 16, 0, 0);
    __builtin_amdgcn_global_load_lds((gas_ptr)(gB1 + ks), (las_ptr)lB1, 16, 0, 0);
    __syncthreads();
    bf16x8 af[4], bfr[4];
#pragma unroll
    for (int m = 0; m < 4; m++) af[m]  = *(const bf16x8*)(lAc + offA[m]);
#pragma unroll
    for (int n = 0; n < 4; n++) bfr[n] = *(const bf16x8*)(lBc + offB[n]);
#pragma unroll
    for (int m = 0; m < 4; m++)
#pragma unroll
      for (int n = 0; n < 4; n++)
        acc[m][n] = __builtin_amdgcn_mfma_f32_16x16x32_bf16(af[m], bfr[n], acc[m][n], 0, 0, 0);
  }

  // epilogue: row = m0+wr*64+m*16+(lane>>4)*4+r, col = n0+wc*64+n*16+(lane&15)
#pragma unroll
  for (int n = 0; n < 4; n++){
    int col = n0 + wc*64 + n*16 + la;
    const bool second = (col >= SPLIT);
    float bv = second ? bias1[col - SPLIT] : bias0[col];
#pragma unroll
    for (int m = 0; m < 4; m++){
      int rbase = m0 + wr*64 + m*16 + lb*4;
#pragma unroll
      for (int r = 0; r < 4; r++){
        int row = rbase + r;
        size_t idx = (size_t)row * N + col;
        float v = acc[m][n][r] + bv;
        if constexpr (EPI == 0) Cf[idx] = v + auxF[idx];
        if constexpr (EPI == 1) {
          if (!second) Cb0[(size_t)row * SPLIT + col] = f32_to_bf16_rne(gelu_exact(v));
          else         Cb1[(size_t)row * (N - SPLIT) + (col - SPLIT)] = f32_to_bf16_rne(v);
        }
        if constexpr (EPI == 2) Cb0[idx] = f32_to_bf16_rne(v);
        if constexpr (EPI == 3) Cb0[idx] = f32_to_bf16_rne(v * bf16_to_f32(auxB[idx]));
      }
    }
  }
}

// ---------------------------------------------------------------------------
// Convert + transpose: in[R][C] f32 -> out[C][R] bf16. 64x64 tiles.
// ---------------------------------------------------------------------------
__global__ __launch_bounds__(256)
void cvt_transpose(const float* __restrict__ in, uint16_t* __restrict__ out, int R, int C)
{
  __shared__ float tile[64][65];
  const int r0 = blockIdx.y * 64, c0 = blockIdx.x * 64;
  const int t = threadIdx.x;
  const int lc = (t & 15) * 4;
  const int lr0 = t >> 4;
#pragma unroll
  for (int j = 0; j < 4; j++){
    int lr = lr0 + j*16;
    float4 v = *(const float4*)(in + (size_t)(r0 + lr) * C + c0 + lc);
    tile[lr][lc+0] = v.x; tile[lr][lc+1] = v.y; tile[lr][lc+2] = v.z; tile[lr][lc+3] = v.w;
  }
  __syncthreads();
  const int oc = t >> 2;
  const int rseg = (t & 3) * 16;
  alignas(16) uint16_t tmp[16];
#pragma unroll
  for (int j = 0; j < 16; j++) tmp[j] = f32_to_bf16_rne(tile[rseg + j][oc]);
  uint4* dst = (uint4*)(out + (size_t)(c0 + oc) * R + r0 + rseg);
  dst[0] = *(const uint4*)(&tmp[0]);
  dst[1] = *(const uint4*)(&tmp[8]);
}

// ---------------------------------------------------------------------------
// RMSNorm: per row of D f32 -> bf16. grid = rows, block = 256 (8 elems/thread).
// ---------------------------------------------------------------------------
__global__ __launch_bounds__(256)
void rmsnorm_kernel(const float* __restrict__ x, const float* __restrict__ w,
                    uint16_t* __restrict__ out, int D)
{
  const int row = blockIdx.x;
  const float* xr = x + (size_t)row * D;
  const int base = threadIdx.x * 8;
  float4 va = *(const float4*)(xr + base);
  float4 vb = *(const float4*)(xr + base + 4);
  float ss = va.x*va.x + va.y*va.y + va.z*va.z + va.w*va.w
           + vb.x*vb.x + vb.y*vb.y + vb.z*vb.z + vb.w*vb.w;
#pragma unroll
  for (int o = 32; o > 0; o >>= 1) ss += __shfl_xor(ss, o);
  __shared__ float red[4];
  if ((threadIdx.x & 63) == 0) red[threadIdx.x >> 6] = ss;
  __syncthreads();
  float tot = red[0] + red[1] + red[2] + red[3];
  float inv = rsqrtf(tot / (float)D + 1e-8f);
  float4 wa = *(const float4*)(w + base);
  float4 wb = *(const float4*)(w + base + 4);
  alignas(16) uint16_t tmp[8];
  tmp[0] = f32_to_bf16_rne(va.x * wa.x * inv);
  tmp[1] = f32_to_bf16_rne(va.y * wa.y * inv);
  tmp[2] = f32_to_bf16_rne(va.z * wa.z * inv);
  tmp[3] = f32_to_bf16_rne(va.w * wa.w * inv);
  tmp[4] = f32_to_bf16_rne(vb.x * wb.x * inv);
  tmp[5] = f32_to_bf16_rne(vb.y * wb.y * inv);
  tmp[6] = f32_to_bf16_rne(vb.z * wb.z * inv);
  tmp[7] = f32_to_bf16_rne(vb.w * wb.w * inv);
  *(uint4*)(out + (size_t)row * D + base) = *(const uint4*)tmp;
}

// ---------------------------------------------------------------------------
// Depthwise causal conv K=4 along t, bf16 in/out. grid (H/256, S/128, B)
// ---------------------------------------------------------------------------
__global__ __launch_bounds__(256)
void conv_kernel(const uint16_t* __restrict__ xin, const float* __restrict__ cw,
                 const float* __restrict__ cb, uint16_t* __restrict__ yout,
                 int S, int H)
{
  const int h = blockIdx.x * 256 + threadIdx.x;
  const int b = blockIdx.z;
  const int t0 = blockIdx.y * 128;
  const float w0 = cw[h], w1 = cw[H + h], w2 = cw[2*H + h], w3 = cw[3*H + h];
  const float bias = cb[h];
  const size_t colbase = (size_t)b * S * H + h;
  float xm3 = (t0 >= 3) ? bf16_to_f32(xin[colbase + (size_t)(t0-3)*H]) : 0.f;
  float xm2 = (t0 >= 2) ? bf16_to_f32(xin[colbase + (size_t)(t0-2)*H]) : 0.f;
  float xm1 = (t0 >= 1) ? bf16_to_f32(xin[colbase + (size_t)(t0-1)*H]) : 0.f;
  for (int t = t0; t < t0 + 128; ++t){
    size_t idx = colbase + (size_t)t * H;
    float xt = bf16_to_f32(xin[idx]);
    float y = w0*xm3 + w1*xm2 + w2*xm1 + w3*xt + bias;
    yout[idx] = f32_to_bf16_rne(y);
    xm3 = xm2; xm2 = xm1; xm1 = xt;
  }
}

// ---------------------------------------------------------------------------
// RG-LRU chunked scan over bf16 inputs. gpre[M][2H]: col h = r-preact,
// col H+h = i-preact. convb[M][H] = conv output (the x of the LRU).
// a = exp(-8*softplus(ap)*sigmoid(r)), b = sqrt(-expm1(2*log_a))*sigmoid(i)*x.
// ---------------------------------------------------------------------------
__device__ __forceinline__ void rglru_ab(float rp, float ip, float xc, float coef,
                                         float& a, float& bb)
{
  float r  = 1.f / (1.f + expf(-rp));
  float la = coef * r;
  a = expf(la);
  float mult = sqrtf(-expm1f(2.f * la));
  float ig = 1.f / (1.f + expf(-ip));
  bb = mult * ig * xc;
}

__global__ __launch_bounds__(256)
void scan_phase1(const uint16_t* __restrict__ gpre, const uint16_t* __restrict__ convb,
                 const float* __restrict__ ap,
                 float* __restrict__ SA, float* __restrict__ SB,
                 int S, int H, int T0, int NC)
{
  const int h = blockIdx.x * 256 + threadIdx.x;
  const int j = blockIdx.y, b = blockIdx.z;
  const float coef = -8.f * log1pf(expf(ap[h]));
  size_t rowb = (size_t)b * S + (size_t)j * T0;
  float A = 1.f, Bc = 0.f;
  for (int t = 0; t < T0; ++t){
    size_t row = rowb + t;
    float rp = bf16_to_f32(gpre[row * 2 * H + h]);
    float ip = bf16_to_f32(gpre[row * 2 * H + H + h]);
    float xc = bf16_to_f32(convb[row * H + h]);
    float a, bb; rglru_ab(rp, ip, xc, coef, a, bb);
    A *= a; Bc = a * Bc + bb;
  }
  size_t o = ((size_t)b * NC + j) * H + h;
  SA[o] = A; SB[o] = Bc;
}

__global__ __launch_bounds__(256)
void scan_phase2(const float* __restrict__ SA, const float* __restrict__ SB,
                 float* __restrict__ SH, int H, int NC)
{
  const int h = blockIdx.x * 256 + threadIdx.x;
  const int b = blockIdx.y;
  float hh = 0.f;
  for (int j = 0; j < NC; ++j){
    size_t o = ((size_t)b * NC + j) * H + h;
    SH[o] = hh;
    hh = SA[o] * hh + SB[o];
  }
}

__global__ __launch_bounds__(256)
void scan_phase3(const uint16_t* __restrict__ gpre, const uint16_t* __restrict__ convb,
                 const float* __restrict__ ap, const float* __restrict__ SH,
                 const uint16_t* __restrict__ left, uint16_t* __restrict__ lr,
                 int S, int H, int T0, int NC)
{
  const int h = blockIdx.x * 256 + threadIdx.x;
  const int j = blockIdx.y, b = blockIdx.z;
  const float coef = -8.f * log1pf(expf(ap[h]));
  float hh = SH[((size_t)b * NC + j) * H + h];
  size_t rowb = (size_t)b * S + (size_t)j * T0;
  for (int t = 0; t < T0; ++t){
    size_t row = rowb + t;
    float rp = bf16_to_f32(gpre[row * 2 * H + h]);
    float ip = bf16_to_f32(gpre[row * 2 * H + H + h]);
    float xc = bf16_to_f32(convb[row * H + h]);
    float a, bb; rglru_ab(rp, ip, xc, coef, a, bb);
    hh = a * hh + bb;
    lr[row * H + h] = f32_to_bf16_rne(bf16_to_f32(left[row * H + h]) * hh);
  }
}

// ---------------------------------------------------------------------------
extern "C" void kernel_launch(void* const* d_in, const int* in_sizes, int n_in,
                              void* d_out, int out_size, void* d_ws, size_t ws_size,
                              hipStream_t stream)
{
  const int B = 2, S = 2048, D = 2048, H = 2048, F = 6144;
  const int M = B * S;            // 4096
  const int NC = 32, T0 = S / NC; // scan chunking

  const float* x       = (const float*)d_in[0];
  const float* norm1_w = (const float*)d_in[1];
  const float* left_W  = (const float*)d_in[2];
  const float* left_b  = (const float*)d_in[3];
  const float* right_W = (const float*)d_in[4];
  const float* right_b = (const float*)d_in[5];
  const float* conv_w  = (const float*)d_in[6];
  const float* conv_b  = (const float*)d_in[7];
  const float* ga_W    = (const float*)d_in[8];
  const float* ga_b    = (const float*)d_in[9];
  const float* gx_W    = (const float*)d_in[10];
  const float* gx_b    = (const float*)d_in[11];
  const float* a_param = (const float*)d_in[12];
  const float* out_W   = (const float*)d_in[13];
  const float* out_b   = (const float*)d_in[14];
  const float* norm2_w = (const float*)d_in[15];
  const float* up1_W   = (const float*)d_in[16];
  const float* up1_b   = (const float*)d_in[17];
  const float* up2_W   = (const float*)d_in[18];
  const float* up2_b   = (const float*)d_in[19];
  const float* down_W  = (const float*)d_in[20];
  const float* down_b  = (const float*)d_in[21];

  char* ws = (char*)d_ws;
  size_t off = 0;
  auto alloc = [&](size_t bytes) -> char* {
    char* p = ws + off; off += (bytes + 255) & ~(size_t)255; return p;
  };
  // All block sizes are multiples of 256B, so overlays line up exactly:
  //   T1 [M][F] bf16 (50.33 MB) === XN + LEFT + RPRE (3 x 16.78 MB), dead by step 8
  //   G  [M][F] bf16 (50.33 MB) === CONVB + GPRE (16.78 + 33.55 MB), dead by step 9
  uint16_t* WT    = (uint16_t*)alloc((size_t)F * D * 2);   // weight bf16^T scratch
  uint16_t* XN    = (uint16_t*)alloc((size_t)M * D * 2);   // rmsnorm1 out
  uint16_t* LEFT  = (uint16_t*)alloc((size_t)M * H * 2);   // gelu(left) bf16
  uint16_t* RPRE  = (uint16_t*)alloc((size_t)M * H * 2);   // right preact (conv in)
  uint16_t* CONVB = (uint16_t*)alloc((size_t)M * H * 2);   // conv out (gate A + scan x)
  uint16_t* GPRE  = (uint16_t*)alloc((size_t)M * 2 * H * 2); // [M][2H] r|i preacts
  uint16_t* LR    = (uint16_t*)alloc((size_t)M * H * 2);   // left * h
  float*    X1    = (float*)   alloc((size_t)M * D * 4);   // residual stream (f32)
  uint16_t* X1N   = (uint16_t*)alloc((size_t)M * D * 2);   // rmsnorm2 out
  float*    SA    = (float*)   alloc((size_t)B * NC * H * 4);
  float*    SB    = (float*)   alloc((size_t)B * NC * H * 4);
  float*    SHB   = (float*)   alloc((size_t)B * NC * H * 4);
  uint16_t* T1    = XN;    // overlay: [M][F] bf16, live steps 8-9
  uint16_t* G     = CONVB; // overlay: [M][F] bf16, live steps 9-10

  if (off > ws_size) {
    fprintf(stderr, "kernel_launch: ws too small, need %zu have %zu\n", off, ws_size);
    return;
  }

  float* OUT = (float*)d_out;
  dim3 blk(256);

  // 1. xn = rmsnorm(x)
  rmsnorm_kernel<<<M, blk, 0, stream>>>(x, norm1_w, XN, D);

  // 2. merged left|right GEMM: N=4096, split 2048. left half -> gelu bf16, right -> raw bf16
  cvt_transpose<<<dim3(H/64, D/64), blk, 0, stream>>>(left_W, WT, D, H);
  cvt_transpose<<<dim3(H/64, D/64), blk, 0, stream>>>(right_W, WT + (size_t)H * D, D, H);
  gemm_kernel<1><<<dim3((2*H)/128, M/128), blk, 0, stream>>>(
      XN, WT, left_b, right_b, nullptr, nullptr, nullptr, LEFT, RPRE, M, 2*H, D, H);

  // 3. conv (causal depthwise) bf16 -> bf16
  conv_kernel<<<dim3(H/256, S/128, B), blk, 0, stream>>>(RPRE, conv_w, conv_b, CONVB, S, H);

  // 4. merged gate GEMM: GPRE[M][2H] = conv @ [ga_W | gx_W] + [ga_b | gx_b]
  cvt_transpose<<<dim3(H/64, H/64), blk, 0, stream>>>(ga_W, WT, H, H);
  cvt_transpose<<<dim3(H/64, H/64), blk, 0, stream>>>(gx_W, WT + (size_t)H * H, H, H);
  gemm_kernel<2><<<dim3((2*H)/128, M/128), blk, 0, stream>>>(
      CONVB, WT, ga_b, gx_b, nullptr, nullptr, nullptr, GPRE, nullptr, M, 2*H, H, H);

  // 5. rg-lru chunked scan; phase3 fuses lr = bf16(left * h)
  scan_phase1<<<dim3(H/256, NC, B), blk, 0, stream>>>(GPRE, CONVB, a_param, SA, SB, S, H, T0, NC);
  scan_phase2<<<dim3(H/256, B), blk, 0, stream>>>(SA, SB, SHB, H, NC);
  scan_phase3<<<dim3(H/256, NC, B), blk, 0, stream>>>(GPRE, CONVB, a_param, SHB, LEFT, LR, S, H, T0, NC);

  // 6. x1 = lr @ out_W + out_b + x   (f32 residual stream)
  cvt_transpose<<<dim3(D/64, H/64), blk, 0, stream>>>(out_W, WT, H, D);
  gemm_kernel<0><<<dim3(D/128, M/128), blk, 0, stream>>>(
      LR, WT, out_b, out_b, x, nullptr, X1, nullptr, nullptr, M, D, H, D);

  // 7. x1n = rmsnorm(x1)
  rmsnorm_kernel<<<M, blk, 0, stream>>>(X1, norm2_w, X1N, D);

  // 8. t1 = gelu(x1n @ up1_W + up1_b)  (EPI1 with SPLIT=N -> all gelu; overlays XN/LEFT/RPRE)
  cvt_transpose<<<dim3(F/64, D/64), blk, 0, stream>>>(up1_W, WT, D, F);
  gemm_kernel<1><<<dim3(F/128, M/128), blk, 0, stream>>>(
      X1N, WT, up1_b, up1_b, nullptr, nullptr, nullptr, T1, nullptr, M, F, D, F);

  // 9. g = bf16(t1 * (x1n @ up2_W + up2_b))  (overlays CONVB/GPRE)
  cvt_transpose<<<dim3(F/64, D/64), blk, 0, stream>>>(up2_W, WT, D, F);
  gemm_kernel<3><<<dim3(F/128, M/128), blk, 0, stream>>>(
      X1N, WT, up2_b, up2_b, nullptr, T1, nullptr, G, nullptr, M, F, D, F);

  // 10. out = g @ down_W + down_b + x1
  cvt_transpose<<<dim3(D/64, F/64), blk, 0, stream>>>(down_W, WT, F, D);
  gemm_kernel<0><<<dim3(D/128, M/128), blk, 0, stream>>>(
      G, WT, down_b, down_b, X1, nullptr, OUT, nullptr, nullptr, M, D, F, D);
}

// Round 5
// 902.621 us; speedup vs baseline: 1.0737x; 1.0545x over previous
//
#include <hip/hip_runtime.h>
#include <cstdint>
#include <cstdio>

typedef __bf16 bf16x8 __attribute__((ext_vector_type(8)));
typedef float  f32x4  __attribute__((ext_vector_type(4)));
typedef const __attribute__((address_space(1))) void* gas_ptr;
typedef __attribute__((address_space(3))) void* las_ptr;

__device__ __forceinline__ uint16_t f32_to_bf16_rne(float f){
  uint32_t u = __builtin_bit_cast(uint32_t, f);
  u += 0x7FFFu + ((u >> 16) & 1u);
  return (uint16_t)(u >> 16);
}
__device__ __forceinline__ float bf16_to_f32(uint16_t h){
  uint32_t u = (uint32_t)h << 16;
  return __builtin_bit_cast(float, u);
}
__device__ __forceinline__ float gelu_exact(float x){
  return 0.5f * x * (1.f + erff(x * 0.7071067811865475f));
}

// ---------------------------------------------------------------------------
// 8-phase-style GEMM (learn_hip m201 template): C[M,N] = A[M,K] * Bt[N,K]^T.
// BM x 256 tile, BK=64, 512 threads = 8 waves (2 M x 4 N), wave out BM/2 x 64.
// Double-buffered LDS (2*(BM+256)*128 bytes), global_load_lds staging with
// pre-swizzled global source (G21), XOR swizzle chunk^=row&7 on ds_read_b128,
// counted vmcnt (never 0 in main loop), raw s_barrier, setprio around MFMA.
// EPI 0: Cf = v + auxF      EPI 1: col<SPLIT ? Cb0=gelu : Cb1=raw (split bufs)
// EPI 2: Cb0 = v            EPI 3: Cb0 = v * auxB
// ---------------------------------------------------------------------------
template<int EPI, int BM>
__global__ __launch_bounds__(512, 2)
void gemm8(const uint16_t* __restrict__ A, const uint16_t* __restrict__ Bt,
           const float* __restrict__ bias0, const float* __restrict__ bias1,
           const float* __restrict__ auxF, const uint16_t* __restrict__ auxB,
           float* __restrict__ Cf, uint16_t* __restrict__ Cb0, uint16_t* __restrict__ Cb1,
           int M, int N, int K, int SPLIT)
{
  constexpr int BN = 256;
  constexpr int M_REP = BM / 32;      // 8 (BM=256) or 4 (BM=128)
  constexpr int MH    = M_REP / 2;
  constexpr int LOADS_A = BM / 64;    // 4 or 2
  constexpr int LOADS_B = BN / 64;    // 4
  constexpr int LTOT  = LOADS_A + LOADS_B;
  constexpr int ABYTES = 2 * BM * 128;   // A region size (2 buffers)
  __shared__ alignas(16) char smem[(2 * (BM + BN)) * 128];

  const int tid  = threadIdx.x;
  const int wid  = tid >> 6;
  const int lane = tid & 63;
  const int wm = wid >> 2, wn = wid & 3;
  const int la = lane & 15, lq = lane >> 4;
  const int n0 = blockIdx.x * BN;
  const int m0 = blockIdx.y * BM;

  // --- staging addressing: thread t covers slot (l*512+t); row = slot>>3,
  // phys chunk c = t&7. LDS stays LINEAR (slot*16); the global source chunk is
  // pre-swizzled g = c ^ (row&7)  (row&7 == rt&7 since l*64 is 0 mod 8).
  const int rt = tid >> 3, ct = tid & 7;
  const int gs = ct ^ (rt & 7);
  const uint16_t* srcA = A  + (size_t)(m0 + rt) * K + gs * 8;
  const uint16_t* srcB = Bt + (size_t)(n0 + rt) * K + gs * 8;

  // --- read addressing: logical chunk (kk*4+lq) at row -> phys ^ (row&7);
  // row = 16*frag + la so row&7 == la&7.
  const int rowAb = (wm * (BM / 2) + la) * 128;
  const int rowBb = (wn * 64 + la) * 128;
  const int ck0 = ((lq)     ^ (la & 7)) * 16;   // kk=0
  const int ck1 = ((4 + lq) ^ (la & 7)) * 16;   // kk=1

  f32x4 acc[M_REP][4];
  const f32x4 fz = {0.f, 0.f, 0.f, 0.f};
#pragma unroll
  for (int m = 0; m < M_REP; ++m)
#pragma unroll
    for (int n = 0; n < 4; ++n) acc[m][n] = fz;

  bf16x8 aF[MH][2];        // A frags of current m-half
  bf16x8 bF[2][2][2];      // B frags, both n-halves live

  const int NT = K >> 6;   // K-tiles of 64

#define STAGE(KT, CUR) do {                                                   \
    const uint16_t* sa_ = srcA + (size_t)(KT) * 64;                           \
    const uint16_t* sb_ = srcB + (size_t)(KT) * 64;                           \
    _Pragma("unroll")                                                         \
    for (int l = 0; l < LOADS_A; ++l)                                         \
      __builtin_amdgcn_global_load_lds((gas_ptr)(sa_ + (size_t)l * 64 * K),   \
          (las_ptr)(smem + (CUR) * BM * 128 + (l * 512 + tid) * 16), 16, 0, 0);\
    _Pragma("unroll")                                                         \
    for (int l = 0; l < LOADS_B; ++l)                                         \
      __builtin_amdgcn_global_load_lds((gas_ptr)(sb_ + (size_t)l * 64 * K),   \
          (las_ptr)(smem + ABYTES + (CUR) * BN * 128 + (l * 512 + tid) * 16), \
          16, 0, 0);                                                          \
  } while (0)

#define LDA(MHS, CUR) do {                                                    \
    _Pragma("unroll")                                                         \
    for (int mq = 0; mq < MH; ++mq) {                                         \
      int ro_ = (CUR) * BM * 128 + rowAb + ((MHS) * MH + mq) * 2048;          \
      aF[mq][0] = *(const bf16x8*)(smem + ro_ + ck0);                         \
      aF[mq][1] = *(const bf16x8*)(smem + ro_ + ck1);                         \
    }                                                                         \
  } while (0)

#define LDB(NH, CUR) do {                                                     \
    _Pragma("unroll")                                                         \
    for (int nq = 0; nq < 2; ++nq) {                                          \
      int ro_ = ABYTES + (CUR) * BN * 128 + rowBb + ((NH) * 2 + nq) * 2048;   \
      bF[NH][nq][0] = *(const bf16x8*)(smem + ro_ + ck0);                     \
      bF[NH][nq][1] = *(const bf16x8*)(smem + ro_ + ck1);                     \
    }                                                                         \
  } while (0)

#define MM(MHS, NH) do {                                                      \
    _Pragma("unroll")                                                         \
    for (int mq = 0; mq < MH; ++mq)                                           \
      _Pragma("unroll")                                                       \
      for (int nq = 0; nq < 2; ++nq) {                                        \
        acc[(MHS)*MH+mq][(NH)*2+nq] = __builtin_amdgcn_mfma_f32_16x16x32_bf16(\
            aF[mq][0], bF[NH][nq][0], acc[(MHS)*MH+mq][(NH)*2+nq], 0, 0, 0);  \
        acc[(MHS)*MH+mq][(NH)*2+nq] = __builtin_amdgcn_mfma_f32_16x16x32_bf16(\
            aF[mq][1], bF[NH][nq][1], acc[(MHS)*MH+mq][(NH)*2+nq], 0, 0, 0);  \
      }                                                                       \
  } while (0)

#define BARR()  __builtin_amdgcn_s_barrier()
#define SCH()   __builtin_amdgcn_sched_barrier(0)
#define LGKM0() asm volatile("s_waitcnt lgkmcnt(0)" ::: "memory")

  // prologue: stage tiles 0,1; wait tile 0 (counted), barrier
  STAGE(0, 0);
  STAGE(1, 1);
  asm volatile("s_waitcnt vmcnt(%0)" :: "i"(LTOT) : "memory");
  BARR(); SCH();

  for (int kt = 0; kt < NT; ++kt) {
    const int cur = kt & 1;
    // phase 0: read B half 0 + A half 0 -> MFMA quadrant (0,0)
    LDB(0, cur); LDA(0, cur);
    SCH(); BARR(); LGKM0(); SCH();
    __builtin_amdgcn_s_setprio(1); MM(0, 0); __builtin_amdgcn_s_setprio(0);
    SCH(); BARR(); SCH();
    // phase 1: read B half 1 -> MFMA (0,1)
    LDB(1, cur);
    SCH(); BARR(); LGKM0(); SCH();
    __builtin_amdgcn_s_setprio(1); MM(0, 1); __builtin_amdgcn_s_setprio(0);
    SCH(); BARR(); SCH();
    // phase 2: read A half 1 -> MFMA (1,0)
    LDA(1, cur);
    SCH(); BARR(); LGKM0(); SCH();
    __builtin_amdgcn_s_setprio(1); MM(1, 0); __builtin_amdgcn_s_setprio(0);
    SCH(); BARR(); SCH();
    // phase 3: stage tile kt+2 into buf[cur] (all reads of cur done) -> MFMA (1,1)
    if (kt + 2 < NT) STAGE(kt + 2, cur);
    SCH(); BARR(); LGKM0(); SCH();
    __builtin_amdgcn_s_setprio(1); MM(1, 1); __builtin_amdgcn_s_setprio(0);
    SCH();
    if (kt + 2 < NT) asm volatile("s_waitcnt vmcnt(%0)" :: "i"(LTOT) : "memory");
    else             asm volatile("s_waitcnt vmcnt(0)" ::: "memory");
    BARR(); SCH();
  }

#undef STAGE
#undef LDA
#undef LDB
#undef MM
#undef BARR
#undef SCH
#undef LGKM0

  // epilogue: row = m0 + wm*(BM/2) + m*16 + lq*4 + r, col = n0 + wn*64 + n*16 + la
#pragma unroll
  for (int n = 0; n < 4; ++n) {
    int col = n0 + wn * 64 + n * 16 + la;
    const bool second = (col >= SPLIT);
    float bv = second ? bias1[col - SPLIT] : bias0[col];
#pragma unroll
    for (int m = 0; m < M_REP; ++m) {
      int rbase = m0 + wm * (BM / 2) + m * 16 + lq * 4;
#pragma unroll
      for (int r = 0; r < 4; ++r) {
        int row = rbase + r;
        size_t idx = (size_t)row * N + col;
        float v = acc[m][n][r] + bv;
        if constexpr (EPI == 0) Cf[idx] = v + auxF[idx];
        if constexpr (EPI == 1) {
          if (!second) Cb0[(size_t)row * SPLIT + col] = f32_to_bf16_rne(gelu_exact(v));
          else         Cb1[(size_t)row * (N - SPLIT) + (col - SPLIT)] = f32_to_bf16_rne(v);
        }
        if constexpr (EPI == 2) Cb0[idx] = f32_to_bf16_rne(v);
        if constexpr (EPI == 3) Cb0[idx] = f32_to_bf16_rne(v * bf16_to_f32(auxB[idx]));
      }
    }
  }
}

// ---------------------------------------------------------------------------
// Convert + transpose: in[R][C] f32 -> out[C][R] bf16. 64x64 tiles.
// ---------------------------------------------------------------------------
__global__ __launch_bounds__(256)
void cvt_transpose(const float* __restrict__ in, uint16_t* __restrict__ out, int R, int C)
{
  __shared__ float tile[64][65];
  const int r0 = blockIdx.y * 64, c0 = blockIdx.x * 64;
  const int t = threadIdx.x;
  const int lc = (t & 15) * 4;
  const int lr0 = t >> 4;
#pragma unroll
  for (int j = 0; j < 4; j++){
    int lr = lr0 + j*16;
    float4 v = *(const float4*)(in + (size_t)(r0 + lr) * C + c0 + lc);
    tile[lr][lc+0] = v.x; tile[lr][lc+1] = v.y; tile[lr][lc+2] = v.z; tile[lr][lc+3] = v.w;
  }
  __syncthreads();
  const int oc = t >> 2;
  const int rseg = (t & 3) * 16;
  alignas(16) uint16_t tmp[16];
#pragma unroll
  for (int j = 0; j < 16; j++) tmp[j] = f32_to_bf16_rne(tile[rseg + j][oc]);
  uint4* dst = (uint4*)(out + (size_t)(c0 + oc) * R + r0 + rseg);
  dst[0] = *(const uint4*)(&tmp[0]);
  dst[1] = *(const uint4*)(&tmp[8]);
}

// ---------------------------------------------------------------------------
// RMSNorm: per row of D f32 -> bf16. grid = rows, block = 256 (8 elems/thread).
// ---------------------------------------------------------------------------
__global__ __launch_bounds__(256)
void rmsnorm_kernel(const float* __restrict__ x, const float* __restrict__ w,
                    uint16_t* __restrict__ out, int D)
{
  const int row = blockIdx.x;
  const float* xr = x + (size_t)row * D;
  const int base = threadIdx.x * 8;
  float4 va = *(const float4*)(xr + base);
  float4 vb = *(const float4*)(xr + base + 4);
  float ss = va.x*va.x + va.y*va.y + va.z*va.z + va.w*va.w
           + vb.x*vb.x + vb.y*vb.y + vb.z*vb.z + vb.w*vb.w;
#pragma unroll
  for (int o = 32; o > 0; o >>= 1) ss += __shfl_xor(ss, o);
  __shared__ float red[4];
  if ((threadIdx.x & 63) == 0) red[threadIdx.x >> 6] = ss;
  __syncthreads();
  float tot = red[0] + red[1] + red[2] + red[3];
  float inv = rsqrtf(tot / (float)D + 1e-8f);
  float4 wa = *(const float4*)(w + base);
  float4 wb = *(const float4*)(w + base + 4);
  alignas(16) uint16_t tmp[8];
  tmp[0] = f32_to_bf16_rne(va.x * wa.x * inv);
  tmp[1] = f32_to_bf16_rne(va.y * wa.y * inv);
  tmp[2] = f32_to_bf16_rne(va.z * wa.z * inv);
  tmp[3] = f32_to_bf16_rne(va.w * wa.w * inv);
  tmp[4] = f32_to_bf16_rne(vb.x * wb.x * inv);
  tmp[5] = f32_to_bf16_rne(vb.y * wb.y * inv);
  tmp[6] = f32_to_bf16_rne(vb.z * wb.z * inv);
  tmp[7] = f32_to_bf16_rne(vb.w * wb.w * inv);
  *(uint4*)(out + (size_t)row * D + base) = *(const uint4*)tmp;
}

// ---------------------------------------------------------------------------
// Depthwise causal conv K=4 along t, bf16 in/out. grid (H/256, S/128, B)
// ---------------------------------------------------------------------------
__global__ __launch_bounds__(256)
void conv_kernel(const uint16_t* __restrict__ xin, const float* __restrict__ cw,
                 const float* __restrict__ cb, uint16_t* __restrict__ yout,
                 int S, int H)
{
  const int h = blockIdx.x * 256 + threadIdx.x;
  const int b = blockIdx.z;
  const int t0 = blockIdx.y * 128;
  const float w0 = cw[h], w1 = cw[H + h], w2 = cw[2*H + h], w3 = cw[3*H + h];
  const float bias = cb[h];
  const size_t colbase = (size_t)b * S * H + h;
  float xm3 = (t0 >= 3) ? bf16_to_f32(xin[colbase + (size_t)(t0-3)*H]) : 0.f;
  float xm2 = (t0 >= 2) ? bf16_to_f32(xin[colbase + (size_t)(t0-2)*H]) : 0.f;
  float xm1 = (t0 >= 1) ? bf16_to_f32(xin[colbase + (size_t)(t0-1)*H]) : 0.f;
  for (int t = t0; t < t0 + 128; ++t){
    size_t idx = colbase + (size_t)t * H;
    float xt = bf16_to_f32(xin[idx]);
    float y = w0*xm3 + w1*xm2 + w2*xm1 + w3*xt + bias;
    yout[idx] = f32_to_bf16_rne(y);
    xm3 = xm2; xm2 = xm1; xm1 = xt;
  }
}

// ---------------------------------------------------------------------------
// RG-LRU chunked scan over bf16 inputs. gpre[M][2H]: col h = r-preact,
// col H+h = i-preact. convb[M][H] = conv output (the x of the LRU).
// ---------------------------------------------------------------------------
__device__ __forceinline__ void rglru_ab(float rp, float ip, float xc, float coef,
                                         float& a, float& bb)
{
  float r  = 1.f / (1.f + expf(-rp));
  float la = coef * r;
  a = expf(la);
  float mult = sqrtf(-expm1f(2.f * la));
  float ig = 1.f / (1.f + expf(-ip));
  bb = mult * ig * xc;
}

__global__ __launch_bounds__(256)
void scan_phase1(const uint16_t* __restrict__ gpre, const uint16_t* __restrict__ convb,
                 const float* __restrict__ ap,
                 float* __restrict__ SA, float* __restrict__ SB,
                 int S, int H, int T0, int NC)
{
  const int h = blockIdx.x * 256 + threadIdx.x;
  const int j = blockIdx.y, b = blockIdx.z;
  const float coef = -8.f * log1pf(expf(ap[h]));
  size_t rowb = (size_t)b * S + (size_t)j * T0;
  float A = 1.f, Bc = 0.f;
  for (int t = 0; t < T0; ++t){
    size_t row = rowb + t;
    float rp = bf16_to_f32(gpre[row * 2 * H + h]);
    float ip = bf16_to_f32(gpre[row * 2 * H + H + h]);
    float xc = bf16_to_f32(convb[row * H + h]);
    float a, bb; rglru_ab(rp, ip, xc, coef, a, bb);
    A *= a; Bc = a * Bc + bb;
  }
  size_t o = ((size_t)b * NC + j) * H + h;
  SA[o] = A; SB[o] = Bc;
}

__global__ __launch_bounds__(256)
void scan_phase2(const float* __restrict__ SA, const float* __restrict__ SB,
                 float* __restrict__ SH, int H, int NC)
{
  const int h = blockIdx.x * 256 + threadIdx.x;
  const int b = blockIdx.y;
  float hh = 0.f;
  for (int j = 0; j < NC; ++j){
    size_t o = ((size_t)b * NC + j) * H + h;
    SH[o] = hh;
    hh = SA[o] * hh + SB[o];
  }
}

__global__ __launch_bounds__(256)
void scan_phase3(const uint16_t* __restrict__ gpre, const uint16_t* __restrict__ convb,
                 const float* __restrict__ ap, const float* __restrict__ SH,
                 const uint16_t* __restrict__ left, uint16_t* __restrict__ lr,
                 int S, int H, int T0, int NC)
{
  const int h = blockIdx.x * 256 + threadIdx.x;
  const int j = blockIdx.y, b = blockIdx.z;
  const float coef = -8.f * log1pf(expf(ap[h]));
  float hh = SH[((size_t)b * NC + j) * H + h];
  size_t rowb = (size_t)b * S + (size_t)j * T0;
  for (int t = 0; t < T0; ++t){
    size_t row = rowb + t;
    float rp = bf16_to_f32(gpre[row * 2 * H + h]);
    float ip = bf16_to_f32(gpre[row * 2 * H + H + h]);
    float xc = bf16_to_f32(convb[row * H + h]);
    float a, bb; rglru_ab(rp, ip, xc, coef, a, bb);
    hh = a * hh + bb;
    lr[row * H + h] = f32_to_bf16_rne(bf16_to_f32(left[row * H + h]) * hh);
  }
}

// ---------------------------------------------------------------------------
extern "C" void kernel_launch(void* const* d_in, const int* in_sizes, int n_in,
                              void* d_out, int out_size, void* d_ws, size_t ws_size,
                              hipStream_t stream)
{
  const int B = 2, S = 2048, D = 2048, H = 2048, F = 6144;
  const int M = B * S;            // 4096
  const int NC = 32, T0 = S / NC; // scan chunking

  const float* x       = (const float*)d_in[0];
  const float* norm1_w = (const float*)d_in[1];
  const float* left_W  = (const float*)d_in[2];
  const float* left_b  = (const float*)d_in[3];
  const float* right_W = (const float*)d_in[4];
  const float* right_b = (const float*)d_in[5];
  const float* conv_w  = (const float*)d_in[6];
  const float* conv_b  = (const float*)d_in[7];
  const float* ga_W    = (const float*)d_in[8];
  const float* ga_b    = (const float*)d_in[9];
  const float* gx_W    = (const float*)d_in[10];
  const float* gx_b    = (const float*)d_in[11];
  const float* a_param = (const float*)d_in[12];
  const float* out_W   = (const float*)d_in[13];
  const float* out_b   = (const float*)d_in[14];
  const float* norm2_w = (const float*)d_in[15];
  const float* up1_W   = (const float*)d_in[16];
  const float* up1_b   = (const float*)d_in[17];
  const float* up2_W   = (const float*)d_in[18];
  const float* up2_b   = (const float*)d_in[19];
  const float* down_W  = (const float*)d_in[20];
  const float* down_b  = (const float*)d_in[21];

  char* ws = (char*)d_ws;
  size_t off = 0;
  auto alloc = [&](size_t bytes) -> char* {
    char* p = ws + off; off += (bytes + 255) & ~(size_t)255; return p;
  };
  // Overlays (exact-size, 256-aligned multiples):
  //   T1 [M][F] bf16 === XN + LEFT + RPRE (3 x 16.78 MB), all dead by step 8
  //   G  [M][F] bf16 === CONVB + GPRE (16.78 + 33.55 MB), dead by step 9
  uint16_t* WT    = (uint16_t*)alloc((size_t)F * D * 2);   // weight bf16^T scratch
  uint16_t* XN    = (uint16_t*)alloc((size_t)M * D * 2);   // rmsnorm1 out
  uint16_t* LEFT  = (uint16_t*)alloc((size_t)M * H * 2);   // gelu(left) bf16
  uint16_t* RPRE  = (uint16_t*)alloc((size_t)M * H * 2);   // right preact (conv in)
  uint16_t* CONVB = (uint16_t*)alloc((size_t)M * H * 2);   // conv out
  uint16_t* GPRE  = (uint16_t*)alloc((size_t)M * 2 * H * 2); // [M][2H] r|i preacts
  uint16_t* LR    = (uint16_t*)alloc((size_t)M * H * 2);   // left * h
  float*    X1    = (float*)   alloc((size_t)M * D * 4);   // residual stream (f32)
  uint16_t* X1N   = (uint16_t*)alloc((size_t)M * D * 2);   // rmsnorm2 out
  float*    SA    = (float*)   alloc((size_t)B * NC * H * 4);
  float*    SB    = (float*)   alloc((size_t)B * NC * H * 4);
  float*    SHB   = (float*)   alloc((size_t)B * NC * H * 4);
  uint16_t* T1    = XN;    // overlay: [M][F] bf16, live steps 8-9
  uint16_t* G     = CONVB; // overlay: [M][F] bf16, live steps 9-10

  if (off > ws_size) {
    fprintf(stderr, "kernel_launch: ws too small, need %zu have %zu\n", off, ws_size);
    return;
  }

  float* OUT = (float*)d_out;
  dim3 blk(256);
  dim3 gblk(512);

  // 1. xn = rmsnorm(x)
  rmsnorm_kernel<<<M, blk, 0, stream>>>(x, norm1_w, XN, D);

  // 2. merged left|right GEMM: N=4096, SPLIT=2048 (gelu | raw)
  cvt_transpose<<<dim3(H/64, D/64), blk, 0, stream>>>(left_W, WT, D, H);
  cvt_transpose<<<dim3(H/64, D/64), blk, 0, stream>>>(right_W, WT + (size_t)H * D, D, H);
  gemm8<1, 256><<<dim3((2*H)/256, M/256), gblk, 0, stream>>>(
      XN, WT, left_b, right_b, nullptr, nullptr, nullptr, LEFT, RPRE, M, 2*H, D, H);

  // 3. conv (causal depthwise) bf16 -> bf16
  conv_kernel<<<dim3(H/256, S/128, B), blk, 0, stream>>>(RPRE, conv_w, conv_b, CONVB, S, H);

  // 4. merged gate GEMM: GPRE[M][2H] = conv @ [ga_W | gx_W] + [ga_b | gx_b]
  cvt_transpose<<<dim3(H/64, H/64), blk, 0, stream>>>(ga_W, WT, H, H);
  cvt_transpose<<<dim3(H/64, H/64), blk, 0, stream>>>(gx_W, WT + (size_t)H * H, H, H);
  gemm8<2, 256><<<dim3((2*H)/256, M/256), gblk, 0, stream>>>(
      CONVB, WT, ga_b, gx_b, nullptr, nullptr, nullptr, GPRE, nullptr, M, 2*H, H, H);

  // 5. rg-lru chunked scan; phase3 fuses lr = bf16(left * h)
  scan_phase1<<<dim3(H/256, NC, B), blk, 0, stream>>>(GPRE, CONVB, a_param, SA, SB, S, H, T0, NC);
  scan_phase2<<<dim3(H/256, B), blk, 0, stream>>>(SA, SB, SHB, H, NC);
  scan_phase3<<<dim3(H/256, NC, B), blk, 0, stream>>>(GPRE, CONVB, a_param, SHB, LEFT, LR, S, H, T0, NC);

  // 6. x1 = lr @ out_W + out_b + x   (f32 residual; 128x256 tile -> 256 blocks)
  cvt_transpose<<<dim3(D/64, H/64), blk, 0, stream>>>(out_W, WT, H, D);
  gemm8<0, 128><<<dim3(D/256, M/128), gblk, 0, stream>>>(
      LR, WT, out_b, out_b, x, nullptr, X1, nullptr, nullptr, M, D, H, D);

  // 7. x1n = rmsnorm(x1)
  rmsnorm_kernel<<<M, blk, 0, stream>>>(X1, norm2_w, X1N, D);

  // 8. t1 = gelu(x1n @ up1_W + up1_b)  (SPLIT=F -> all gelu; overlays XN/LEFT/RPRE)
  cvt_transpose<<<dim3(F/64, D/64), blk, 0, stream>>>(up1_W, WT, D, F);
  gemm8<1, 256><<<dim3(F/256, M/256), gblk, 0, stream>>>(
      X1N, WT, up1_b, up1_b, nullptr, nullptr, nullptr, T1, nullptr, M, F, D, F);

  // 9. g = bf16(t1 * (x1n @ up2_W + up2_b))  (overlays CONVB/GPRE)
  cvt_transpose<<<dim3(F/64, D/64), blk, 0, stream>>>(up2_W, WT, D, F);
  gemm8<3, 256><<<dim3(F/256, M/256), gblk, 0, stream>>>(
      X1N, WT, up2_b, up2_b, nullptr, T1, nullptr, G, nullptr, M, F, D, F);

  // 10. out = g @ down_W + down_b + x1  (128x256 tile, K=6144)
  cvt_transpose<<<dim3(D/64, F/64), blk, 0, stream>>>(down_W, WT, F, D);
  gemm8<0, 128><<<dim3(D/256, M/128), gblk, 0, stream>>>(
      G, WT, down_b, down_b, X1, nullptr, OUT, nullptr, nullptr, M, D, F, D);
}

// Round 6
// 864.184 us; speedup vs baseline: 1.1214x; 1.0445x over previous
//
#include <hip/hip_runtime.h>
#include <cstdint>
#include <cstdio>

typedef __bf16 bf16x8 __attribute__((ext_vector_type(8)));
typedef float  f32x4  __attribute__((ext_vector_type(4)));
typedef const __attribute__((address_space(1))) void* gas_ptr;
typedef __attribute__((address_space(3))) void* las_ptr;

__device__ __forceinline__ uint16_t f32_to_bf16_rne(float f){
  uint32_t u = __builtin_bit_cast(uint32_t, f);
  u += 0x7FFFu + ((u >> 16) & 1u);
  return (uint16_t)(u >> 16);
}
__device__ __forceinline__ float bf16_to_f32(uint16_t h){
  uint32_t u = (uint32_t)h << 16;
  return __builtin_bit_cast(float, u);
}
__device__ __forceinline__ float gelu_exact(float x){
  return 0.5f * x * (1.f + erff(x * 0.7071067811865475f));
}

// ---------------------------------------------------------------------------
// 8-phase GEMM (m201-style): C[M,N] = A[M,K](bf16) * Bt[N,K](bf16)^T.
// BM x 256 tile, BK=64, 512 threads = 8 waves (2 M x 4 N).
// Changes vs r5: NO sched_barrier spam (m141), staging spread across phases
// (m196: B of kt+2 at phase 2, A at phase 3), bijective XCD swizzle (T1).
// Counted vmcnt (never 0 mid-loop), raw s_barrier, setprio around MFMA.
// EPI 0: Cf = v + auxF      EPI 1: col<SPLIT ? Cb0=gelu : Cb1=raw (split bufs)
// EPI 2: Cb0 = v            EPI 3: Cb0 = v * auxB
// ---------------------------------------------------------------------------
template<int EPI, int BM>
__global__ __launch_bounds__(512, 2)
void gemm8(const uint16_t* __restrict__ A, const uint16_t* __restrict__ Bt,
           const float* __restrict__ bias0, const float* __restrict__ bias1,
           const float* __restrict__ auxF, const uint16_t* __restrict__ auxB,
           float* __restrict__ Cf, uint16_t* __restrict__ Cb0, uint16_t* __restrict__ Cb1,
           int M, int N, int K, int SPLIT)
{
  constexpr int BN = 256;
  constexpr int M_REP = BM / 32;      // 8 (BM=256) or 4 (BM=128)
  constexpr int MH    = M_REP / 2;
  constexpr int LOADS_A = BM / 64;    // 4 or 2
  constexpr int LOADS_B = BN / 64;    // 4
  constexpr int LTOT  = LOADS_A + LOADS_B;
  constexpr int ABYTES = 2 * BM * 128;   // A region size (2 buffers)
  __shared__ alignas(16) char smem[(2 * (BM + BN)) * 128];

  const int tid  = threadIdx.x;
  const int lane = tid & 63;
  const int wid  = tid >> 6;
  const int wm = wid >> 2, wn = wid & 3;
  const int la = lane & 15, lq = lane >> 4;

  // bijective XCD-aware block swizzle (nwg % 8 == 0 for all our grids)
  const int gx = gridDim.x;
  int bid = blockIdx.y * gx + blockIdx.x;
  const int nwg = gx * gridDim.y;
  if ((nwg & 7) == 0) bid = (bid & 7) * (nwg >> 3) + (bid >> 3);
  const int n0 = (bid % gx) * BN;
  const int m0 = (bid / gx) * BM;

  // staging: thread t covers slot (l*512+t); row rt = t>>3, phys chunk t&7.
  // LDS linear; global source chunk pre-swizzled gs = (t&7) ^ (rt&7).
  const int rt = tid >> 3;
  const int gs = (tid & 7) ^ (rt & 7);
  const uint16_t* srcA = A  + (size_t)(m0 + rt) * K + gs * 8;
  const uint16_t* srcB = Bt + (size_t)(n0 + rt) * K + gs * 8;

  // reads: logical chunk (kk*4+lq) at row -> phys = logical ^ (row&7); row&7 = la&7.
  const int rowAb = (wm * (BM / 2) + la) * 128;
  const int rowBb = (wn * 64 + la) * 128;
  const int ck0 = ((lq)     ^ (la & 7)) * 16;
  const int ck1 = ((4 + lq) ^ (la & 7)) * 16;

  f32x4 acc[M_REP][4];
  const f32x4 fz = {0.f, 0.f, 0.f, 0.f};
#pragma unroll
  for (int m = 0; m < M_REP; ++m)
#pragma unroll
    for (int n = 0; n < 4; ++n) acc[m][n] = fz;

  bf16x8 aF[MH][2];
  bf16x8 bF[2][2][2];

  const int NT = K >> 6;

#define STAGE_A(KT, CUR) do {                                                 \
    const uint16_t* sa_ = srcA + (size_t)(KT) * 64;                           \
    _Pragma("unroll")                                                         \
    for (int l = 0; l < LOADS_A; ++l)                                         \
      __builtin_amdgcn_global_load_lds((gas_ptr)(sa_ + (size_t)l * 64 * K),   \
          (las_ptr)(smem + (CUR) * BM * 128 + (l * 512 + tid) * 16), 16, 0, 0);\
  } while (0)

#define STAGE_B(KT, CUR) do {                                                 \
    const uint16_t* sb_ = srcB + (size_t)(KT) * 64;                           \
    _Pragma("unroll")                                                         \
    for (int l = 0; l < LOADS_B; ++l)                                         \
      __builtin_amdgcn_global_load_lds((gas_ptr)(sb_ + (size_t)l * 64 * K),   \
          (las_ptr)(smem + ABYTES + (CUR) * BN * 128 + (l * 512 + tid) * 16), \
          16, 0, 0);                                                          \
  } while (0)

#define LDA(MHS, CUR) do {                                                    \
    _Pragma("unroll")                                                         \
    for (int mq = 0; mq < MH; ++mq) {                                         \
      int ro_ = (CUR) * BM * 128 + rowAb + ((MHS) * MH + mq) * 2048;          \
      aF[mq][0] = *(const bf16x8*)(smem + ro_ + ck0);                         \
      aF[mq][1] = *(const bf16x8*)(smem + ro_ + ck1);                         \
    }                                                                         \
  } while (0)

#define LDB(NH, CUR) do {                                                     \
    _Pragma("unroll")                                                         \
    for (int nq = 0; nq < 2; ++nq) {                                          \
      int ro_ = ABYTES + (CUR) * BN * 128 + rowBb + ((NH) * 2 + nq) * 2048;   \
      bF[NH][nq][0] = *(const bf16x8*)(smem + ro_ + ck0);                     \
      bF[NH][nq][1] = *(const bf16x8*)(smem + ro_ + ck1);                     \
    }                                                                         \
  } while (0)

#define MM(MHS, NH) do {                                                      \
    _Pragma("unroll")                                                         \
    for (int mq = 0; mq < MH; ++mq)                                           \
      _Pragma("unroll")                                                       \
      for (int nq = 0; nq < 2; ++nq) {                                        \
        acc[(MHS)*MH+mq][(NH)*2+nq] = __builtin_amdgcn_mfma_f32_16x16x32_bf16(\
            aF[mq][0], bF[NH][nq][0], acc[(MHS)*MH+mq][(NH)*2+nq], 0, 0, 0);  \
        acc[(MHS)*MH+mq][(NH)*2+nq] = __builtin_amdgcn_mfma_f32_16x16x32_bf16(\
            aF[mq][1], bF[NH][nq][1], acc[(MHS)*MH+mq][(NH)*2+nq], 0, 0, 0);  \
      }                                                                       \
  } while (0)

#define BARR()  __builtin_amdgcn_s_barrier()
#define LGKM0() asm volatile("s_waitcnt lgkmcnt(0)" ::: "memory")

  // prologue: stage tiles 0,1; wait tile 0 (counted), barrier
  STAGE_A(0, 0); STAGE_B(0, 0);
  STAGE_A(1, 1); STAGE_B(1, 1);
  asm volatile("s_waitcnt vmcnt(%0)" :: "i"(LTOT) : "memory");
  BARR();

  for (int kt = 0; kt < NT; ++kt) {
    const int cur = kt & 1;
    const bool pf = (kt + 2 < NT);
    // phase 0: read B half0 + A half0 -> MFMA (0,0)
    LDB(0, cur); LDA(0, cur);
    BARR(); LGKM0();
    __builtin_amdgcn_s_setprio(1); MM(0, 0); __builtin_amdgcn_s_setprio(0);
    BARR();
    // phase 1: read B half1 -> MFMA (0,1)
    LDB(1, cur);
    BARR(); LGKM0();
    __builtin_amdgcn_s_setprio(1); MM(0, 1); __builtin_amdgcn_s_setprio(0);
    BARR();
    // phase 2: read A half1; stage B(kt+2) into cur-B (B reads of cur done)
    LDA(1, cur);
    if (pf) STAGE_B(kt + 2, cur);
    BARR(); LGKM0();
    __builtin_amdgcn_s_setprio(1); MM(1, 0); __builtin_amdgcn_s_setprio(0);
    BARR();
    // phase 3: stage A(kt+2) into cur-A (A reads of cur done) -> MFMA (1,1)
    if (pf) STAGE_A(kt + 2, cur);
    BARR(); LGKM0();
    __builtin_amdgcn_s_setprio(1); MM(1, 1); __builtin_amdgcn_s_setprio(0);
    if (pf) asm volatile("s_waitcnt vmcnt(%0)" :: "i"(LTOT) : "memory");
    else    asm volatile("s_waitcnt vmcnt(0)" ::: "memory");
    BARR();
  }

#undef STAGE_A
#undef STAGE_B
#undef LDA
#undef LDB
#undef MM
#undef BARR
#undef LGKM0

  // epilogue: row = m0 + wm*(BM/2) + m*16 + lq*4 + r, col = n0 + wn*64 + n*16 + la
#pragma unroll
  for (int n = 0; n < 4; ++n) {
    int col = n0 + wn * 64 + n * 16 + la;
    const bool second = (col >= SPLIT);
    float bv = second ? bias1[col - SPLIT] : bias0[col];
#pragma unroll
    for (int m = 0; m < M_REP; ++m) {
      int rbase = m0 + wm * (BM / 2) + m * 16 + lq * 4;
#pragma unroll
      for (int r = 0; r < 4; ++r) {
        int row = rbase + r;
        size_t idx = (size_t)row * N + col;
        float v = acc[m][n][r] + bv;
        if constexpr (EPI == 0) Cf[idx] = v + auxF[idx];
        if constexpr (EPI == 1) {
          if (!second) Cb0[(size_t)row * SPLIT + col] = f32_to_bf16_rne(gelu_exact(v));
          else         Cb1[(size_t)row * (N - SPLIT) + (col - SPLIT)] = f32_to_bf16_rne(v);
        }
        if constexpr (EPI == 2) Cb0[idx] = f32_to_bf16_rne(v);
        if constexpr (EPI == 3) Cb0[idx] = f32_to_bf16_rne(v * bf16_to_f32(auxB[idx]));
      }
    }
  }
}

// ---------------------------------------------------------------------------
// Convert + transpose: in[R][C] f32 -> out[C][R] bf16. 64x64 tiles.
// ---------------------------------------------------------------------------
__global__ __launch_bounds__(256)
void cvt_transpose(const float* __restrict__ in, uint16_t* __restrict__ out, int R, int C)
{
  __shared__ float tile[64][65];
  const int r0 = blockIdx.y * 64, c0 = blockIdx.x * 64;
  const int t = threadIdx.x;
  const int lc = (t & 15) * 4;
  const int lr0 = t >> 4;
#pragma unroll
  for (int j = 0; j < 4; j++){
    int lr = lr0 + j*16;
    float4 v = *(const float4*)(in + (size_t)(r0 + lr) * C + c0 + lc);
    tile[lr][lc+0] = v.x; tile[lr][lc+1] = v.y; tile[lr][lc+2] = v.z; tile[lr][lc+3] = v.w;
  }
  __syncthreads();
  const int oc = t >> 2;
  const int rseg = (t & 3) * 16;
  alignas(16) uint16_t tmp[16];
#pragma unroll
  for (int j = 0; j < 16; j++) tmp[j] = f32_to_bf16_rne(tile[rseg + j][oc]);
  uint4* dst = (uint4*)(out + (size_t)(c0 + oc) * R + r0 + rseg);
  dst[0] = *(const uint4*)(&tmp[0]);
  dst[1] = *(const uint4*)(&tmp[8]);
}

// ---------------------------------------------------------------------------
// RMSNorm: per row of D f32 -> bf16. grid = rows, block = 256 (8 elems/thread).
// ---------------------------------------------------------------------------
__global__ __launch_bounds__(256)
void rmsnorm_kernel(const float* __restrict__ x, const float* __restrict__ w,
                    uint16_t* __restrict__ out, int D)
{
  const int row = blockIdx.x;
  const float* xr = x + (size_t)row * D;
  const int base = threadIdx.x * 8;
  float4 va = *(const float4*)(xr + base);
  float4 vb = *(const float4*)(xr + base + 4);
  float ss = va.x*va.x + va.y*va.y + va.z*va.z + va.w*va.w
           + vb.x*vb.x + vb.y*vb.y + vb.z*vb.z + vb.w*vb.w;
#pragma unroll
  for (int o = 32; o > 0; o >>= 1) ss += __shfl_xor(ss, o);
  __shared__ float red[4];
  if ((threadIdx.x & 63) == 0) red[threadIdx.x >> 6] = ss;
  __syncthreads();
  float tot = red[0] + red[1] + red[2] + red[3];
  float inv = rsqrtf(tot / (float)D + 1e-8f);
  float4 wa = *(const float4*)(w + base);
  float4 wb = *(const float4*)(w + base + 4);
  alignas(16) uint16_t tmp[8];
  tmp[0] = f32_to_bf16_rne(va.x * wa.x * inv);
  tmp[1] = f32_to_bf16_rne(va.y * wa.y * inv);
  tmp[2] = f32_to_bf16_rne(va.z * wa.z * inv);
  tmp[3] = f32_to_bf16_rne(va.w * wa.w * inv);
  tmp[4] = f32_to_bf16_rne(vb.x * wb.x * inv);
  tmp[5] = f32_to_bf16_rne(vb.y * wb.y * inv);
  tmp[6] = f32_to_bf16_rne(vb.z * wb.z * inv);
  tmp[7] = f32_to_bf16_rne(vb.w * wb.w * inv);
  *(uint4*)(out + (size_t)row * D + base) = *(const uint4*)tmp;
}

// ---------------------------------------------------------------------------
// Depthwise causal conv K=4 along t, bf16 in/out. grid (H/256, S/128, B)
// ---------------------------------------------------------------------------
__global__ __launch_bounds__(256)
void conv_kernel(const uint16_t* __restrict__ xin, const float* __restrict__ cw,
                 const float* __restrict__ cb, uint16_t* __restrict__ yout,
                 int S, int H)
{
  const int h = blockIdx.x * 256 + threadIdx.x;
  const int b = blockIdx.z;
  const int t0 = blockIdx.y * 128;
  const float w0 = cw[h], w1 = cw[H + h], w2 = cw[2*H + h], w3 = cw[3*H + h];
  const float bias = cb[h];
  const size_t colbase = (size_t)b * S * H + h;
  float xm3 = (t0 >= 3) ? bf16_to_f32(xin[colbase + (size_t)(t0-3)*H]) : 0.f;
  float xm2 = (t0 >= 2) ? bf16_to_f32(xin[colbase + (size_t)(t0-2)*H]) : 0.f;
  float xm1 = (t0 >= 1) ? bf16_to_f32(xin[colbase + (size_t)(t0-1)*H]) : 0.f;
  for (int t = t0; t < t0 + 128; ++t){
    size_t idx = colbase + (size_t)t * H;
    float xt = bf16_to_f32(xin[idx]);
    float y = w0*xm3 + w1*xm2 + w2*xm1 + w3*xt + bias;
    yout[idx] = f32_to_bf16_rne(y);
    xm3 = xm2; xm2 = xm1; xm1 = xt;
  }
}

// ---------------------------------------------------------------------------
// RG-LRU chunked scan over bf16 inputs. gpre[M][2H]: col h = r-preact,
// col H+h = i-preact. convb[M][H] = conv output (the x of the LRU).
// ---------------------------------------------------------------------------
__device__ __forceinline__ void rglru_ab(float rp, float ip, float xc, float coef,
                                         float& a, float& bb)
{
  float r  = 1.f / (1.f + expf(-rp));
  float la = coef * r;
  a = expf(la);
  float mult = sqrtf(-expm1f(2.f * la));
  float ig = 1.f / (1.f + expf(-ip));
  bb = mult * ig * xc;
}

__global__ __launch_bounds__(256)
void scan_phase1(const uint16_t* __restrict__ gpre, const uint16_t* __restrict__ convb,
                 const float* __restrict__ ap,
                 float* __restrict__ SA, float* __restrict__ SB,
                 int S, int H, int T0, int NC)
{
  const int h = blockIdx.x * 256 + threadIdx.x;
  const int j = blockIdx.y, b = blockIdx.z;
  const float coef = -8.f * log1pf(expf(ap[h]));
  size_t rowb = (size_t)b * S + (size_t)j * T0;
  float A = 1.f, Bc = 0.f;
  for (int t = 0; t < T0; ++t){
    size_t row = rowb + t;
    float rp = bf16_to_f32(gpre[row * 2 * H + h]);
    float ip = bf16_to_f32(gpre[row * 2 * H + H + h]);
    float xc = bf16_to_f32(convb[row * H + h]);
    float a, bb; rglru_ab(rp, ip, xc, coef, a, bb);
    A *= a; Bc = a * Bc + bb;
  }
  size_t o = ((size_t)b * NC + j) * H + h;
  SA[o] = A; SB[o] = Bc;
}

__global__ __launch_bounds__(256)
void scan_phase2(const float* __restrict__ SA, const float* __restrict__ SB,
                 float* __restrict__ SH, int H, int NC)
{
  const int h = blockIdx.x * 256 + threadIdx.x;
  const int b = blockIdx.y;
  float hh = 0.f;
  for (int j = 0; j < NC; ++j){
    size_t o = ((size_t)b * NC + j) * H + h;
    SH[o] = hh;
    hh = SA[o] * hh + SB[o];
  }
}

__global__ __launch_bounds__(256)
void scan_phase3(const uint16_t* __restrict__ gpre, const uint16_t* __restrict__ convb,
                 const float* __restrict__ ap, const float* __restrict__ SH,
                 const uint16_t* __restrict__ left, uint16_t* __restrict__ lr,
                 int S, int H, int T0, int NC)
{
  const int h = blockIdx.x * 256 + threadIdx.x;
  const int j = blockIdx.y, b = blockIdx.z;
  const float coef = -8.f * log1pf(expf(ap[h]));
  float hh = SH[((size_t)b * NC + j) * H + h];
  size_t rowb = (size_t)b * S + (size_t)j * T0;
  for (int t = 0; t < T0; ++t){
    size_t row = rowb + t;
    float rp = bf16_to_f32(gpre[row * 2 * H + h]);
    float ip = bf16_to_f32(gpre[row * 2 * H + H + h]);
    float xc = bf16_to_f32(convb[row * H + h]);
    float a, bb; rglru_ab(rp, ip, xc, coef, a, bb);
    hh = a * hh + bb;
    lr[row * H + h] = f32_to_bf16_rne(bf16_to_f32(left[row * H + h]) * hh);
  }
}

// ---------------------------------------------------------------------------
extern "C" void kernel_launch(void* const* d_in, const int* in_sizes, int n_in,
                              void* d_out, int out_size, void* d_ws, size_t ws_size,
                              hipStream_t stream)
{
  const int B = 2, S = 2048, D = 2048, H = 2048, F = 6144;
  const int M = B * S;            // 4096
  const int NC = 32, T0 = S / NC; // scan chunking

  const float* x       = (const float*)d_in[0];
  const float* norm1_w = (const float*)d_in[1];
  const float* left_W  = (const float*)d_in[2];
  const float* left_b  = (const float*)d_in[3];
  const float* right_W = (const float*)d_in[4];
  const float* right_b = (const float*)d_in[5];
  const float* conv_w  = (const float*)d_in[6];
  const float* conv_b  = (const float*)d_in[7];
  const float* ga_W    = (const float*)d_in[8];
  const float* ga_b    = (const float*)d_in[9];
  const float* gx_W    = (const float*)d_in[10];
  const float* gx_b    = (const float*)d_in[11];
  const float* a_param = (const float*)d_in[12];
  const float* out_W   = (const float*)d_in[13];
  const float* out_b   = (const float*)d_in[14];
  const float* norm2_w = (const float*)d_in[15];
  const float* up1_W   = (const float*)d_in[16];
  const float* up1_b   = (const float*)d_in[17];
  const float* up2_W   = (const float*)d_in[18];
  const float* up2_b   = (const float*)d_in[19];
  const float* down_W  = (const float*)d_in[20];
  const float* down_b  = (const float*)d_in[21];

  char* ws = (char*)d_ws;
  size_t off = 0;
  auto alloc = [&](size_t bytes) -> char* {
    char* p = ws + off; off += (bytes + 255) & ~(size_t)255; return p;
  };
  // Overlays (exact-size, 256-aligned multiples):
  //   T1 [M][F] bf16 === XN + LEFT + RPRE (3 x 16.78 MB), all dead by step 8
  //   G  [M][F] bf16 === CONVB + GPRE (16.78 + 33.55 MB), dead by step 9
  uint16_t* WT    = (uint16_t*)alloc((size_t)F * D * 2);   // weight bf16^T scratch
  uint16_t* XN    = (uint16_t*)alloc((size_t)M * D * 2);   // rmsnorm1 out
  uint16_t* LEFT  = (uint16_t*)alloc((size_t)M * H * 2);   // gelu(left) bf16
  uint16_t* RPRE  = (uint16_t*)alloc((size_t)M * H * 2);   // right preact (conv in)
  uint16_t* CONVB = (uint16_t*)alloc((size_t)M * H * 2);   // conv out
  uint16_t* GPRE  = (uint16_t*)alloc((size_t)M * 2 * H * 2); // [M][2H] r|i preacts
  uint16_t* LR    = (uint16_t*)alloc((size_t)M * H * 2);   // left * h
  float*    X1    = (float*)   alloc((size_t)M * D * 4);   // residual stream (f32)
  uint16_t* X1N   = (uint16_t*)alloc((size_t)M * D * 2);   // rmsnorm2 out
  float*    SA    = (float*)   alloc((size_t)B * NC * H * 4);
  float*    SB    = (float*)   alloc((size_t)B * NC * H * 4);
  float*    SHB   = (float*)   alloc((size_t)B * NC * H * 4);
  uint16_t* T1    = XN;    // overlay: [M][F] bf16, live steps 8-9
  uint16_t* G     = CONVB; // overlay: [M][F] bf16, live steps 9-10

  if (off > ws_size) {
    fprintf(stderr, "kernel_launch: ws too small, need %zu have %zu\n", off, ws_size);
    return;
  }

  float* OUT = (float*)d_out;
  dim3 blk(256);
  dim3 gblk(512);

  // 1. xn = rmsnorm(x)
  rmsnorm_kernel<<<M, blk, 0, stream>>>(x, norm1_w, XN, D);

  // 2. merged left|right GEMM: N=4096, SPLIT=2048 (gelu | raw)
  cvt_transpose<<<dim3(H/64, D/64), blk, 0, stream>>>(left_W, WT, D, H);
  cvt_transpose<<<dim3(H/64, D/64), blk, 0, stream>>>(right_W, WT + (size_t)H * D, D, H);
  gemm8<1, 256><<<dim3((2*H)/256, M/256), gblk, 0, stream>>>(
      XN, WT, left_b, right_b, nullptr, nullptr, nullptr, LEFT, RPRE, M, 2*H, D, H);

  // 3. conv (causal depthwise) bf16 -> bf16
  conv_kernel<<<dim3(H/256, S/128, B), blk, 0, stream>>>(RPRE, conv_w, conv_b, CONVB, S, H);

  // 4. merged gate GEMM: GPRE[M][2H] = conv @ [ga_W | gx_W] + [ga_b | gx_b]
  cvt_transpose<<<dim3(H/64, H/64), blk, 0, stream>>>(ga_W, WT, H, H);
  cvt_transpose<<<dim3(H/64, H/64), blk, 0, stream>>>(gx_W, WT + (size_t)H * H, H, H);
  gemm8<2, 256><<<dim3((2*H)/256, M/256), gblk, 0, stream>>>(
      CONVB, WT, ga_b, gx_b, nullptr, nullptr, nullptr, GPRE, nullptr, M, 2*H, H, H);

  // 5. rg-lru chunked scan; phase3 fuses lr = bf16(left * h)
  scan_phase1<<<dim3(H/256, NC, B), blk, 0, stream>>>(GPRE, CONVB, a_param, SA, SB, S, H, T0, NC);
  scan_phase2<<<dim3(H/256, B), blk, 0, stream>>>(SA, SB, SHB, H, NC);
  scan_phase3<<<dim3(H/256, NC, B), blk, 0, stream>>>(GPRE, CONVB, a_param, SHB, LEFT, LR, S, H, T0, NC);

  // 6. x1 = lr @ out_W + out_b + x   (f32 residual; 128x256 tile -> 256 blocks)
  cvt_transpose<<<dim3(D/64, H/64), blk, 0, stream>>>(out_W, WT, H, D);
  gemm8<0, 128><<<dim3(D/256, M/128), gblk, 0, stream>>>(
      LR, WT, out_b, out_b, x, nullptr, X1, nullptr, nullptr, M, D, H, D);

  // 7. x1n = rmsnorm(x1)
  rmsnorm_kernel<<<M, blk, 0, stream>>>(X1, norm2_w, X1N, D);

  // 8. t1 = gelu(x1n @ up1_W + up1_b)  (SPLIT=F -> all gelu; overlays XN/LEFT/RPRE)
  cvt_transpose<<<dim3(F/64, D/64), blk, 0, stream>>>(up1_W, WT, D, F);
  gemm8<1, 256><<<dim3(F/256, M/256), gblk, 0, stream>>>(
      X1N, WT, up1_b, up1_b, nullptr, nullptr, nullptr, T1, nullptr, M, F, D, F);

  // 9. g = bf16(t1 * (x1n @ up2_W + up2_b))  (overlays CONVB/GPRE)
  cvt_transpose<<<dim3(F/64, D/64), blk, 0, stream>>>(up2_W, WT, D, F);
  gemm8<3, 256><<<dim3(F/256, M/256), gblk, 0, stream>>>(
      X1N, WT, up2_b, up2_b, nullptr, T1, nullptr, G, nullptr, M, F, D, F);

  // 10. out = g @ down_W + down_b + x1  (128x256 tile, K=6144)
  cvt_transpose<<<dim3(D/64, F/64), blk, 0, stream>>>(down_W, WT, F, D);
  gemm8<0, 128><<<dim3(D/256, M/128), gblk, 0, stream>>>(
      G, WT, down_b, down_b, X1, nullptr, OUT, nullptr, nullptr, M, D, F, D);
}